// Round 1
// baseline (72.641 us; speedup 1.0000x reference)
//
#include <hip/hip_runtime.h>

#define BLK 256
#define KJ 16                 // j's per thread -> JLANES = 4096 j's per block
#define JLANES (BLK * KJ)     // 4096
#define ITILE 16              // i's per block (wave-uniform scalar loop)
#define GX (8192 / ITILE)     // 512
#define GY (8192 / JLANES)    // 2
#define NSLOTS (GX * GY)      // 1024 blocks, one float4 slot each

__global__ __launch_bounds__(BLK) void svm_partial(
    const float* __restrict__ pred,
    const float2* __restrict__ tg,
    float4* __restrict__ ws_slots) {
  const int tid = threadIdx.x;
  const int i0 = blockIdx.x * ITILE;
  const int j0 = blockIdx.y * JLANES;

  // Per-lane j data: contiguous 64B per lane -> 4x dwordx4 (pred) and
  // 8x dwordx4 (tg). 16B/lane coalescing sweet spot, 12 VMEM total.
  float pj[KJ], tj[KJ];
  {
    const float4* p4 = reinterpret_cast<const float4*>(pred + j0 + tid * KJ);
    #pragma unroll
    for (int q = 0; q < KJ / 4; ++q) {
      const float4 v = p4[q];
      pj[4 * q + 0] = v.x; pj[4 * q + 1] = v.y;
      pj[4 * q + 2] = v.z; pj[4 * q + 3] = v.w;
    }
    const float4* t4 = reinterpret_cast<const float4*>(
        reinterpret_cast<const float*>(tg) + 2 * (j0 + tid * KJ));
    #pragma unroll
    for (int q = 0; q < KJ / 2; ++q) {
      const float4 v = t4[q];          // two float2 (time,event) pairs
      tj[2 * q + 0] = v.x; tj[2 * q + 1] = v.z;
    }
  }

  // Whole i-tile preloaded once: wave-uniform scalar loads, ONE lgkmcnt wait.
  float pi[ITILE], ti[ITILE], ei[ITILE];
  #pragma unroll
  for (int u = 0; u < ITILE; ++u) {
    pi[u] = pred[i0 + u];
    const float2 te = tg[i0 + u];
    ti[u] = te.x; ei[u] = te.y;
  }

  float rank0 = 0.0f, rank1 = 0.0f;   // dual accumulators break the fma chain
  unsigned int cnt = 0u;              // wave-uniform: ballot/popcount (SALU)

  #pragma unroll
  for (int u = 0; u < ITILE; ++u) {
    if (ei[u] == 1.0f) {              // uniform scalar branch, ~half taken
      const float pi1 = pi[u] + 1.0f;
      const float tu = ti[u];
      #pragma unroll
      for (int k = 0; k < KJ; k += 2) {
        {
          const bool m = tj[k] > tu;                      // v_cmp -> mask
          cnt += (unsigned int)__popcll(__ballot(m));     // scalar pipe
          float h = fmaxf(pi1 - pj[k], 0.0f);
          h = m ? h : 0.0f;                               // cndmask
          rank0 = fmaf(h, h, rank0);
        }
        {
          const bool m = tj[k + 1] > tu;
          cnt += (unsigned int)__popcll(__ballot(m));
          float h = fmaxf(pi1 - pj[k + 1], 0.0f);
          h = m ? h : 0.0f;
          rank1 = fmaf(h, h, rank1);
        }
      }
    }
  }
  float rank = rank0 + rank1;

  // Regression term: counted exactly once (y==0 slice, tid<ITILE).
  float reg = 0.0f;
  if (blockIdx.y == 0 && tid < ITILE) {
    const int i = i0 + tid;
    const float p = pred[i];
    const float2 te = tg[i];
    float d = p - te.x;
    if (te.y == 0.0f) d = fmaxf(d, 0.0f);
    reg = d * d;
  }

  // 64-lane shuffle reduction (rank/reg only; cnt is wave-uniform)
  #pragma unroll
  for (int off = 32; off > 0; off >>= 1) {
    rank += __shfl_down(rank, off);
    reg  += __shfl_down(reg, off);
  }

  __shared__ float sr[BLK / 64];
  __shared__ float sg[BLK / 64];
  __shared__ unsigned int sc[BLK / 64];
  const int wave = tid >> 6;
  const int lane = tid & 63;
  if (lane == 0) { sr[wave] = rank; sg[wave] = reg; sc[wave] = cnt; }
  __syncthreads();

  if (tid == 0) {
    const float r = sr[0] + sr[1] + sr[2] + sr[3];
    const float g = sg[0] + sg[1] + sg[2] + sg[3];
    const unsigned int c = sc[0] + sc[1] + sc[2] + sc[3];
    // c <= ITILE*JLANES = 65536: exactly representable in float.
    const int slot = blockIdx.y * GX + blockIdx.x;
    ws_slots[slot] = make_float4(r, g, (float)c, 0.0f);  // one dwordx4 store
  }
}

// Single wave, no barrier; NSLOTS/64 = 16 dwordx4 loads per lane, pipelined.
__global__ __launch_bounds__(64) void svm_finalize(
    const float4* __restrict__ ws_slots,
    float* __restrict__ out, int n) {
  const int tid = threadIdx.x;
  double r = 0.0, g = 0.0, c = 0.0;
  #pragma unroll
  for (int s = tid; s < NSLOTS; s += 64) {
    const float4 v = ws_slots[s];
    r += (double)v.x;
    g += (double)v.y;
    c += (double)v.z;     // each term integral & exact
  }
  #pragma unroll
  for (int off = 32; off > 0; off >>= 1) {
    r += __shfl_down(r, off);
    g += __shfl_down(g, off);
    c += __shfl_down(c, off);
  }
  if (tid == 0) {
    const double cd = (c > 0.0 ? c : 1.0);
    out[0] = (float)(0.5 * r / cd + 0.5 * g / (double)n);
  }
}

extern "C" void kernel_launch(void* const* d_in, const int* in_sizes, int n_in,
                              void* d_out, int out_size, void* d_ws, size_t ws_size,
                              hipStream_t stream) {
  const float* pred = (const float*)d_in[0];
  const float2* tg = (const float2*)d_in[1];
  float* out = (float*)d_out;
  const int n = in_sizes[0];  // 8192

  float4* ws_slots = (float4*)d_ws;

  svm_partial<<<dim3(GX, GY), BLK, 0, stream>>>(pred, tg, ws_slots);
  svm_finalize<<<1, 64, 0, stream>>>(ws_slots, out, n);
}